// Round 1
// baseline (1021.853 us; speedup 1.0000x reference)
//
#include <hip/hip_runtime.h>
#include <hip/hip_bf16.h>

#define B_  32
#define N_  8192
#define C1  64
#define C2  128
#define C3  256
#define KO  40

// ---------- helpers ----------

__device__ __forceinline__ float ftanh(float x) {
    // tanh(x) = 1 - 2/(exp(2x)+1); exact at +-inf saturation
    float e = __expf(2.0f * x);
    float r = __builtin_amdgcn_rcpf(e + 1.0f);
    return fmaf(-2.0f, r, 1.0f);
}

__device__ __forceinline__ float waveMax(float v) {
    v = fmaxf(v, __shfl_xor(v, 32, 64));
    v = fmaxf(v, __shfl_xor(v, 16, 64));
    v = fmaxf(v, __shfl_xor(v, 8, 64));
    v = fmaxf(v, __shfl_xor(v, 4, 64));
    v = fmaxf(v, __shfl_xor(v, 2, 64));
    v = fmaxf(v, __shfl_xor(v, 1, 64));
    return v;
}

// order-preserving float<->uint encoding for atomicMax
__device__ __forceinline__ unsigned encf(float f) {
    unsigned u = __float_as_uint(f);
    return (u & 0x80000000u) ? ~u : (u | 0x80000000u);
}
__device__ __forceinline__ float decf(unsigned e) {
    return __uint_as_float((e & 0x80000000u) ? (e & 0x7fffffffu) : ~e);
}

__device__ __forceinline__ unsigned short f2bf(float f) {
    unsigned u = __float_as_uint(f);
    return (unsigned short)((u + 0x7fffu + ((u >> 16) & 1u)) >> 16);
}

// ---------- kernels ----------

// per-(b,f) max of x over N : 96 rows
__global__ __launch_bounds__(256) void k_rowmax(const float* __restrict__ x,
                                                float* __restrict__ mx1) {
    int row = blockIdx.x;  // b*3+f
    const float* p = x + (size_t)row * N_;
    float m = -1e30f;
    for (int i = threadIdx.x; i < N_; i += 256) m = fmaxf(m, p[i]);
    m = waveMax(m);
    __shared__ float s[4];
    if ((threadIdx.x & 63) == 0) s[threadIdx.x >> 6] = m;
    __syncthreads();
    if (threadIdx.x == 0)
        mx1[row] = fmaxf(fmaxf(s[0], s[1]), fmaxf(s[2], s[3]));
}

__global__ __launch_bounds__(64) void k_beff1(const float* __restrict__ mx1,
                                              const float* __restrict__ w1,
                                              const float* __restrict__ b1,
                                              float* __restrict__ beff1) {
    int b = blockIdx.x, o = threadIdx.x;
    float v = b1[o];
    v -= mx1[b * 3 + 0] * w1[o * 3 + 0];
    v -= mx1[b * 3 + 1] * w1[o * 3 + 1];
    v -= mx1[b * 3 + 2] * w1[o * 3 + 2];
    beff1[b * C1 + o] = v;
}

// pass B: h1 = tanh(W1 x + beff1), accumulate per-(b,o) max -> mx2e
__global__ __launch_bounds__(256) void k_passB(const float* __restrict__ x,
                                               const float* __restrict__ w1,
                                               const float* __restrict__ beff1,
                                               unsigned* __restrict__ mx2e) {
    int bx = blockIdx.x;
    int b = bx >> 5, chunk = bx & 31;
    int n = chunk * 256 + threadIdx.x;
    const float* xb = x + (size_t)b * 3 * N_ + n;
    float x0 = xb[0], x1 = xb[N_], x2 = xb[2 * N_];
    int lane = threadIdx.x & 63;
    for (int o = 0; o < C1; ++o) {
        float a = beff1[b * C1 + o];
        a = fmaf(x0, w1[o * 3 + 0], a);
        a = fmaf(x1, w1[o * 3 + 1], a);
        a = fmaf(x2, w1[o * 3 + 2], a);
        float m = waveMax(ftanh(a));
        if (lane == 0) atomicMax(&mx2e[b * C1 + o], encf(m));
    }
}

__global__ __launch_bounds__(128) void k_beff2(const unsigned* __restrict__ mx2e,
                                               const float* __restrict__ w2,
                                               const float* __restrict__ b2,
                                               float* __restrict__ beff2) {
    __shared__ float m2[C1];
    int b = blockIdx.x, t = threadIdx.x;
    if (t < C1) m2[t] = decf(mx2e[b * C1 + t]);
    __syncthreads();
    float a = b2[t];
#pragma unroll
    for (int f = 0; f < C1; ++f) a -= m2[f] * w2[t * C1 + f];
    beff2[b * C2 + t] = a;
}

// pass C: recompute h1, h2 = tanh(W2 h1 + beff2), max -> mx3e
__global__ __launch_bounds__(256) void k_passC(const float* __restrict__ x,
                                               const float* __restrict__ w1,
                                               const float* __restrict__ beff1,
                                               const float* __restrict__ w2,
                                               const float* __restrict__ beff2,
                                               unsigned* __restrict__ mx3e) {
    int bx = blockIdx.x;
    int b = bx >> 5, chunk = bx & 31;
    int n = chunk * 256 + threadIdx.x;
    const float* xb = x + (size_t)b * 3 * N_ + n;
    float x0 = xb[0], x1 = xb[N_], x2 = xb[2 * N_];
    int lane = threadIdx.x & 63;

    float h1[C1];
#pragma unroll
    for (int o = 0; o < C1; ++o) {
        float a = beff1[b * C1 + o];
        a = fmaf(x0, w1[o * 3 + 0], a);
        a = fmaf(x1, w1[o * 3 + 1], a);
        a = fmaf(x2, w1[o * 3 + 2], a);
        h1[o] = ftanh(a);
    }

    for (int o2 = 0; o2 < C2; o2 += 4) {
        float a0 = beff2[b * C2 + o2 + 0];
        float a1 = beff2[b * C2 + o2 + 1];
        float a2 = beff2[b * C2 + o2 + 2];
        float a3 = beff2[b * C2 + o2 + 3];
#pragma unroll
        for (int f = 0; f < C1; ++f) {
            float h = h1[f];
            a0 = fmaf(h, w2[(o2 + 0) * C1 + f], a0);
            a1 = fmaf(h, w2[(o2 + 1) * C1 + f], a1);
            a2 = fmaf(h, w2[(o2 + 2) * C1 + f], a2);
            a3 = fmaf(h, w2[(o2 + 3) * C1 + f], a3);
        }
        float m0 = waveMax(ftanh(a0));
        float m1 = waveMax(ftanh(a1));
        float m2 = waveMax(ftanh(a2));
        float m3 = waveMax(ftanh(a3));
        if (lane == 0) {
            atomicMax(&mx3e[b * C2 + o2 + 0], encf(m0));
            atomicMax(&mx3e[b * C2 + o2 + 1], encf(m1));
            atomicMax(&mx3e[b * C2 + o2 + 2], encf(m2));
            atomicMax(&mx3e[b * C2 + o2 + 3], encf(m3));
        }
    }
}

__global__ __launch_bounds__(256) void k_beff3(const unsigned* __restrict__ mx3e,
                                               const float* __restrict__ w3,
                                               const float* __restrict__ b3,
                                               float* __restrict__ beff3) {
    __shared__ float m3[C2];
    int b = blockIdx.x, t = threadIdx.x;
    if (t < C2) m3[t] = decf(mx3e[b * C2 + t]);
    __syncthreads();
    float a = b3[t];
#pragma unroll
    for (int f = 0; f < C2; ++f) a -= m3[f] * w3[t * C2 + f];
    beff3[b * C3 + t] = a;
}

// pass D: recompute h1,h2; h3 = tanh(W3 h2 + beff3); g = max_n h3 -> genc
__global__ __launch_bounds__(128) void k_passD(const float* __restrict__ x,
                                               const float* __restrict__ w1,
                                               const float* __restrict__ beff1,
                                               const float* __restrict__ w2,
                                               const float* __restrict__ beff2,
                                               const float* __restrict__ w3,
                                               const float* __restrict__ beff3,
                                               unsigned* __restrict__ genc) {
    __shared__ unsigned h2p[C2 / 2][128];  // packed bf16 pairs, column t private
    int bx = blockIdx.x;
    int b = bx >> 6, chunk = bx & 63;
    int t = threadIdx.x;
    int n = chunk * 128 + t;
    const float* xb = x + (size_t)b * 3 * N_ + n;
    float x0 = xb[0], x1 = xb[N_], x2 = xb[2 * N_];
    int lane = t & 63;

    float h1[C1];
#pragma unroll
    for (int o = 0; o < C1; ++o) {
        float a = beff1[b * C1 + o];
        a = fmaf(x0, w1[o * 3 + 0], a);
        a = fmaf(x1, w1[o * 3 + 1], a);
        a = fmaf(x2, w1[o * 3 + 2], a);
        h1[o] = ftanh(a);
    }

    // layer 2 -> packed bf16 in LDS (each thread owns its own column; no barrier)
    for (int o2 = 0; o2 < C2; o2 += 2) {
        float a0 = beff2[b * C2 + o2 + 0];
        float a1 = beff2[b * C2 + o2 + 1];
#pragma unroll
        for (int f = 0; f < C1; ++f) {
            float h = h1[f];
            a0 = fmaf(h, w2[(o2 + 0) * C1 + f], a0);
            a1 = fmaf(h, w2[(o2 + 1) * C1 + f], a1);
        }
        unsigned p = (unsigned)f2bf(ftanh(a0)) | ((unsigned)f2bf(ftanh(a1)) << 16);
        h2p[o2 >> 1][t] = p;
    }

    // layer 3 + global max pool
    for (int o3 = 0; o3 < C3; o3 += 8) {
        float a[8];
#pragma unroll
        for (int k = 0; k < 8; ++k) a[k] = beff3[b * C3 + o3 + k];
#pragma unroll 4
        for (int q = 0; q < C2 / 2; ++q) {
            unsigned p = h2p[q][t];
            float hlo = __uint_as_float(p << 16);
            float hhi = __uint_as_float(p & 0xffff0000u);
            int f0 = 2 * q, f1 = 2 * q + 1;
#pragma unroll
            for (int k = 0; k < 8; ++k) {
                a[k] = fmaf(hlo, w3[(o3 + k) * C2 + f0], a[k]);
                a[k] = fmaf(hhi, w3[(o3 + k) * C2 + f1], a[k]);
            }
        }
#pragma unroll
        for (int k = 0; k < 8; ++k) {
            float m = waveMax(ftanh(a[k]));
            if (lane == 0) atomicMax(&genc[b * C3 + o3 + k], encf(m));
        }
    }
}

// FC head + log_softmax (one block per batch sample)
__global__ __launch_bounds__(256) void k_fc(const unsigned* __restrict__ genc,
                                            const float* __restrict__ fc1w,
                                            const float* __restrict__ fc1b,
                                            const float* __restrict__ fc2w,
                                            const float* __restrict__ fc2b,
                                            float* __restrict__ out) {
    __shared__ float gs[C3];
    __shared__ float hs[C2];
    __shared__ float vs[KO];
    __shared__ float red[2];
    int b = blockIdx.x, t = threadIdx.x;
    gs[t] = decf(genc[b * C3 + t]);
    __syncthreads();
    if (t < C2) {
        float a = fc1b[t];
#pragma unroll 8
        for (int i = 0; i < C3; ++i) a = fmaf(gs[i], fc1w[t * C3 + i], a);
        hs[t] = ftanh(a);
    }
    __syncthreads();
    if (t < KO) {
        float a = fc2b[t];
#pragma unroll 8
        for (int i = 0; i < C2; ++i) a = fmaf(hs[i], fc2w[t * C2 + i], a);
        vs[t] = ftanh(a);
    }
    __syncthreads();
    if (t == 0) {
        float m = -1e30f;
        for (int j = 0; j < KO; ++j) m = fmaxf(m, vs[j]);
        float s = 0.0f;
        for (int j = 0; j < KO; ++j) s += __expf(vs[j] - m);
        red[0] = m;
        red[1] = __logf(s);
    }
    __syncthreads();
    if (t < KO) out[b * KO + t] = vs[t] - red[0] - red[1];
}

// ---------- launcher ----------

extern "C" void kernel_launch(void* const* d_in, const int* in_sizes, int n_in,
                              void* d_out, int out_size, void* d_ws, size_t ws_size,
                              hipStream_t stream) {
    const float* x    = (const float*)d_in[0];
    const float* w1   = (const float*)d_in[1];
    const float* b1   = (const float*)d_in[2];
    const float* w2   = (const float*)d_in[3];
    const float* b2   = (const float*)d_in[4];
    const float* w3   = (const float*)d_in[5];
    const float* b3   = (const float*)d_in[6];
    const float* fc1w = (const float*)d_in[7];
    const float* fc1b = (const float*)d_in[8];
    const float* fc2w = (const float*)d_in[9];
    const float* fc2b = (const float*)d_in[10];
    float* out = (float*)d_out;

    // workspace layout (floats)
    float* W = (float*)d_ws;
    float*    mx1   = W;                     // 96
    float*    beff1 = W + 96;                // 2048
    unsigned* mx2e  = (unsigned*)(W + 2144); // 2048
    float*    beff2 = W + 4192;              // 4096
    unsigned* mx3e  = (unsigned*)(W + 8288); // 4096
    float*    beff3 = W + 12384;             // 8192
    unsigned* genc  = (unsigned*)(W + 20576);// 8192

    hipMemsetAsync(mx2e, 0, C1 * B_ * sizeof(unsigned), stream);
    hipMemsetAsync(mx3e, 0, C2 * B_ * sizeof(unsigned), stream);
    hipMemsetAsync(genc, 0, C3 * B_ * sizeof(unsigned), stream);

    k_rowmax<<<B_ * 3, 256, 0, stream>>>(x, mx1);
    k_beff1<<<B_, 64, 0, stream>>>(mx1, w1, b1, beff1);
    k_passB<<<B_ * 32, 256, 0, stream>>>(x, w1, beff1, mx2e);
    k_beff2<<<B_, 128, 0, stream>>>(mx2e, w2, b2, beff2);
    k_passC<<<B_ * 32, 256, 0, stream>>>(x, w1, beff1, w2, beff2, mx3e);
    k_beff3<<<B_, 256, 0, stream>>>(mx3e, w3, b3, beff3);
    k_passD<<<B_ * 64, 128, 0, stream>>>(x, w1, beff1, w2, beff2, w3, beff3, genc);
    k_fc<<<B_, 256, 0, stream>>>(genc, fc1w, fc1b, fc2w, fc2b, out);
}

// Round 2
// 275.471 us; speedup vs baseline: 3.7095x; 3.7095x over previous
//
#include <hip/hip_runtime.h>
#include <hip/hip_bf16.h>

#define B_  32
#define N_  8192
#define C1  64
#define C2  128
#define C3  256
#define KO  40

typedef __attribute__((ext_vector_type(8))) short bh8;
typedef __attribute__((ext_vector_type(4))) float f32x4;

union FragU { uint u[4]; bh8 h; };

// ---------- helpers ----------

__device__ __forceinline__ float ftanh(float x) {
    float e = __expf(2.0f * x);
    float r = __builtin_amdgcn_rcpf(e + 1.0f);
    return fmaf(-2.0f, r, 1.0f);
}

__device__ __forceinline__ float waveMax(float v) {
    v = fmaxf(v, __shfl_xor(v, 32, 64));
    v = fmaxf(v, __shfl_xor(v, 16, 64));
    v = fmaxf(v, __shfl_xor(v, 8, 64));
    v = fmaxf(v, __shfl_xor(v, 4, 64));
    v = fmaxf(v, __shfl_xor(v, 2, 64));
    v = fmaxf(v, __shfl_xor(v, 1, 64));
    return v;
}

// order-preserving float<->uint encoding for atomicMax
__device__ __forceinline__ unsigned encf(float f) {
    unsigned u = __float_as_uint(f);
    return (u & 0x80000000u) ? ~u : (u | 0x80000000u);
}
__device__ __forceinline__ float decf(unsigned e) {
    return __uint_as_float((e & 0x80000000u) ? (e & 0x7fffffffu) : ~e);
}

__device__ __forceinline__ unsigned f2bf(float f) {
    unsigned u = __float_as_uint(f);
    return (u + 0x7fffu + ((u >> 16) & 1u)) >> 16;
}
__device__ __forceinline__ unsigned packbf(float a, float b) {
    return f2bf(a) | (f2bf(b) << 16);
}

// ---------- small kernels (unchanged from R1) ----------

__global__ __launch_bounds__(256) void k_rowmax(const float* __restrict__ x,
                                                float* __restrict__ mx1) {
    int row = blockIdx.x;
    const float* p = x + (size_t)row * N_;
    float m = -1e30f;
    for (int i = threadIdx.x; i < N_; i += 256) m = fmaxf(m, p[i]);
    m = waveMax(m);
    __shared__ float s[4];
    if ((threadIdx.x & 63) == 0) s[threadIdx.x >> 6] = m;
    __syncthreads();
    if (threadIdx.x == 0)
        mx1[row] = fmaxf(fmaxf(s[0], s[1]), fmaxf(s[2], s[3]));
}

__global__ __launch_bounds__(64) void k_beff1(const float* __restrict__ mx1,
                                              const float* __restrict__ w1,
                                              const float* __restrict__ b1,
                                              float* __restrict__ beff1) {
    int b = blockIdx.x, o = threadIdx.x;
    float v = b1[o];
    v -= mx1[b * 3 + 0] * w1[o * 3 + 0];
    v -= mx1[b * 3 + 1] * w1[o * 3 + 1];
    v -= mx1[b * 3 + 2] * w1[o * 3 + 2];
    beff1[b * C1 + o] = v;
}

__global__ __launch_bounds__(256) void k_passB(const float* __restrict__ x,
                                               const float* __restrict__ w1,
                                               const float* __restrict__ beff1,
                                               unsigned* __restrict__ mx2e) {
    int bx = blockIdx.x;
    int b = bx >> 5, chunk = bx & 31;
    int n = chunk * 256 + threadIdx.x;
    const float* xb = x + (size_t)b * 3 * N_ + n;
    float x0 = xb[0], x1 = xb[N_], x2 = xb[2 * N_];
    int lane = threadIdx.x & 63;
    for (int o = 0; o < C1; ++o) {
        float a = beff1[b * C1 + o];
        a = fmaf(x0, w1[o * 3 + 0], a);
        a = fmaf(x1, w1[o * 3 + 1], a);
        a = fmaf(x2, w1[o * 3 + 2], a);
        float m = waveMax(ftanh(a));
        if (lane == 0) atomicMax(&mx2e[b * C1 + o], encf(m));
    }
}

__global__ __launch_bounds__(128) void k_beff2(const unsigned* __restrict__ mx2e,
                                               const float* __restrict__ w2,
                                               const float* __restrict__ b2,
                                               float* __restrict__ beff2) {
    __shared__ float m2[C1];
    int b = blockIdx.x, t = threadIdx.x;
    if (t < C1) m2[t] = decf(mx2e[b * C1 + t]);
    __syncthreads();
    float a = b2[t];
#pragma unroll
    for (int f = 0; f < C1; ++f) a -= m2[f] * w2[t * C1 + f];
    beff2[b * C2 + t] = a;
}

__global__ __launch_bounds__(256) void k_beff3(const unsigned* __restrict__ mx3e,
                                               const float* __restrict__ w3,
                                               const float* __restrict__ b3,
                                               float* __restrict__ beff3) {
    __shared__ float m3[C2];
    int b = blockIdx.x, t = threadIdx.x;
    if (t < C2) m3[t] = decf(mx3e[b * C2 + t]);
    __syncthreads();
    float a = b3[t];
#pragma unroll
    for (int f = 0; f < C2; ++f) a -= m3[f] * w3[t * C2 + f];
    beff3[b * C3 + t] = a;
}

// ---------- weight prep: fp32 -> bf16 A-fragments (16x16x32 layout) ----------
// A[m=lane&15][k=quad*8+j]; frag idx = (mt*KSN + ks)*64 + lane, 8 bf16 = uint4.

__global__ __launch_bounds__(256) void k_prep(const float* __restrict__ w2,
                                              const float* __restrict__ w3,
                                              uint4* __restrict__ w2f,
                                              uint4* __restrict__ w3f) {
    int tid = blockIdx.x * 256 + threadIdx.x;  // 0..5119
    const float* src;
    uint4* dst;
    if (tid < 1024) {  // W2: 8 Mt x 2 ks x 64 lanes
        int lane = tid & 63, ks = (tid >> 6) & 1, mt = tid >> 7;
        src = w2 + (mt * 16 + (lane & 15)) * C1 + ks * 32 + (lane >> 4) * 8;
        dst = w2f + tid;
    } else {           // W3: 16 Mt x 4 ks x 64 lanes
        int fj = tid - 1024;
        int lane = fj & 63, ks = (fj >> 6) & 3, mt = fj >> 8;
        src = w3 + (mt * 16 + (lane & 15)) * C2 + ks * 32 + (lane >> 4) * 8;
        dst = w3f + fj;
    }
    uint4 o;
    o.x = packbf(src[0], src[1]);
    o.y = packbf(src[2], src[3]);
    o.z = packbf(src[4], src[5]);
    o.w = packbf(src[6], src[7]);
    *dst = o;
}

// ---------- MFMA passes ----------
// LDS activation layout: arr[k4][n] = uint2 packing bf16 k=4*k4..4*k4+3 for point n.
// B-frag for (ks, quad): k4 = ks*8 + quad*2 (+1) -> two ds_read_b64, conflict-free.

#define MFMA_BF16 __builtin_amdgcn_mfma_f32_16x16x32_bf16

// passC: layer1 (VALU) -> layer2 (MFMA) -> max over points -> mx3e
__global__ __launch_bounds__(256) void k_passC_m(const float* __restrict__ x,
                                                 const float* __restrict__ w1,
                                                 const float* __restrict__ beff1,
                                                 const uint4* __restrict__ w2f,
                                                 const float* __restrict__ beff2,
                                                 unsigned* __restrict__ mx3e) {
    __shared__ uint2 h1d[16][130];
    int b = blockIdx.x >> 6;
    int nbase = (blockIdx.x & 63) * 128;
    int t = threadIdx.x;
    int p = t & 127, hh = t >> 7;
    int lane = t & 63, wv = t >> 6, qd = lane >> 4, ln = lane & 15;

    // phase 0: layer 1 for point p, channels hh*32..+31
    {
        const float* xb = x + (size_t)b * 3 * N_ + nbase + p;
        float x0 = xb[0], x1 = xb[N_], x2 = xb[2 * N_];
#pragma unroll
        for (int q = 0; q < 8; ++q) {
            int c = hh * 32 + q * 4;
            float v[4];
#pragma unroll
            for (int s = 0; s < 4; ++s) {
                float a = beff1[b * C1 + c + s];
                a = fmaf(x0, w1[(c + s) * 3 + 0], a);
                a = fmaf(x1, w1[(c + s) * 3 + 1], a);
                a = fmaf(x2, w1[(c + s) * 3 + 2], a);
                v[s] = ftanh(a);
            }
            h1d[hh * 8 + q][p] = make_uint2(packbf(v[0], v[1]), packbf(v[2], v[3]));
        }
    }
    __syncthreads();

    // layer 2 MFMA: wave wv -> Mtiles {2wv, 2wv+1}
    bh8 wf2[2][2];
    float bb2[2][4];
#pragma unroll
    for (int mi = 0; mi < 2; ++mi) {
        int mt = 2 * wv + mi;
#pragma unroll
        for (int ks = 0; ks < 2; ++ks) {
            FragU fu;
            uint4 w = w2f[(mt * 2 + ks) * 64 + lane];
            fu.u[0] = w.x; fu.u[1] = w.y; fu.u[2] = w.z; fu.u[3] = w.w;
            wf2[mi][ks] = fu.h;
        }
#pragma unroll
        for (int r = 0; r < 4; ++r)
            bb2[mi][r] = beff2[b * C2 + mt * 16 + qd * 4 + r];
    }

    float vmax[2][4];
#pragma unroll
    for (int mi = 0; mi < 2; ++mi)
#pragma unroll
        for (int r = 0; r < 4; ++r) vmax[mi][r] = -1e30f;

    for (int nb = 0; nb < 8; ++nb) {
        int n = nb * 16 + ln;
        f32x4 acc0 = {0.f, 0.f, 0.f, 0.f};
        f32x4 acc1 = {0.f, 0.f, 0.f, 0.f};
#pragma unroll
        for (int ks = 0; ks < 2; ++ks) {
            int k4 = ks * 8 + qd * 2;
            uint2 u0 = h1d[k4][n], u1 = h1d[k4 + 1][n];
            FragU fb;
            fb.u[0] = u0.x; fb.u[1] = u0.y; fb.u[2] = u1.x; fb.u[3] = u1.y;
            acc0 = MFMA_BF16(wf2[0][ks], fb.h, acc0, 0, 0, 0);
            acc1 = MFMA_BF16(wf2[1][ks], fb.h, acc1, 0, 0, 0);
        }
#pragma unroll
        for (int r = 0; r < 4; ++r) {
            vmax[0][r] = fmaxf(vmax[0][r], ftanh(acc0[r] + bb2[0][r]));
            vmax[1][r] = fmaxf(vmax[1][r], ftanh(acc1[r] + bb2[1][r]));
        }
    }

#pragma unroll
    for (int mi = 0; mi < 2; ++mi)
#pragma unroll
        for (int r = 0; r < 4; ++r) {
            float v = vmax[mi][r];
            v = fmaxf(v, __shfl_xor(v, 1, 64));
            v = fmaxf(v, __shfl_xor(v, 2, 64));
            v = fmaxf(v, __shfl_xor(v, 4, 64));
            v = fmaxf(v, __shfl_xor(v, 8, 64));
            if (ln == 0)
                atomicMax(&mx3e[b * C2 + (2 * wv + mi) * 16 + qd * 4 + r], encf(v));
        }
}

// passD: layer1 (VALU) -> layer2 (MFMA, to LDS) -> layer3 (MFMA) -> genc
__global__ __launch_bounds__(256) void k_passD_m(const float* __restrict__ x,
                                                 const float* __restrict__ w1,
                                                 const float* __restrict__ beff1,
                                                 const uint4* __restrict__ w2f,
                                                 const float* __restrict__ beff2,
                                                 const uint4* __restrict__ w3f,
                                                 const float* __restrict__ beff3,
                                                 unsigned* __restrict__ genc) {
    __shared__ uint2 h1d[16][130];
    __shared__ uint2 h2d[32][130];
    int b = blockIdx.x >> 6;
    int nbase = (blockIdx.x & 63) * 128;
    int t = threadIdx.x;
    int p = t & 127, hh = t >> 7;
    int lane = t & 63, wv = t >> 6, qd = lane >> 4, ln = lane & 15;

    // phase 0: layer 1
    {
        const float* xb = x + (size_t)b * 3 * N_ + nbase + p;
        float x0 = xb[0], x1 = xb[N_], x2 = xb[2 * N_];
#pragma unroll
        for (int q = 0; q < 8; ++q) {
            int c = hh * 32 + q * 4;
            float v[4];
#pragma unroll
            for (int s = 0; s < 4; ++s) {
                float a = beff1[b * C1 + c + s];
                a = fmaf(x0, w1[(c + s) * 3 + 0], a);
                a = fmaf(x1, w1[(c + s) * 3 + 1], a);
                a = fmaf(x2, w1[(c + s) * 3 + 2], a);
                v[s] = ftanh(a);
            }
            h1d[hh * 8 + q][p] = make_uint2(packbf(v[0], v[1]), packbf(v[2], v[3]));
        }
    }
    __syncthreads();

    // layer 2 MFMA: wave wv -> Mtiles {2wv, 2wv+1}; write h2 -> LDS
    {
        bh8 wf2[2][2];
        float bb2[2][4];
#pragma unroll
        for (int mi = 0; mi < 2; ++mi) {
            int mt = 2 * wv + mi;
#pragma unroll
            for (int ks = 0; ks < 2; ++ks) {
                FragU fu;
                uint4 w = w2f[(mt * 2 + ks) * 64 + lane];
                fu.u[0] = w.x; fu.u[1] = w.y; fu.u[2] = w.z; fu.u[3] = w.w;
                wf2[mi][ks] = fu.h;
            }
#pragma unroll
            for (int r = 0; r < 4; ++r)
                bb2[mi][r] = beff2[b * C2 + mt * 16 + qd * 4 + r];
        }
        for (int nb = 0; nb < 8; ++nb) {
            int n = nb * 16 + ln;
            f32x4 acc0 = {0.f, 0.f, 0.f, 0.f};
            f32x4 acc1 = {0.f, 0.f, 0.f, 0.f};
#pragma unroll
            for (int ks = 0; ks < 2; ++ks) {
                int k4 = ks * 8 + qd * 2;
                uint2 u0 = h1d[k4][n], u1 = h1d[k4 + 1][n];
                FragU fb;
                fb.u[0] = u0.x; fb.u[1] = u0.y; fb.u[2] = u1.x; fb.u[3] = u1.y;
                acc0 = MFMA_BF16(wf2[0][ks], fb.h, acc0, 0, 0, 0);
                acc1 = MFMA_BF16(wf2[1][ks], fb.h, acc1, 0, 0, 0);
            }
            // rows (2wv+mi)*16 + qd*4 + r are 4 consecutive -> one uint2 (k4 = mt*4+qd)
            {
                float v0 = ftanh(acc0[0] + bb2[0][0]);
                float v1 = ftanh(acc0[1] + bb2[0][1]);
                float v2 = ftanh(acc0[2] + bb2[0][2]);
                float v3 = ftanh(acc0[3] + bb2[0][3]);
                h2d[(2 * wv + 0) * 4 + qd][n] = make_uint2(packbf(v0, v1), packbf(v2, v3));
                v0 = ftanh(acc1[0] + bb2[1][0]);
                v1 = ftanh(acc1[1] + bb2[1][1]);
                v2 = ftanh(acc1[2] + bb2[1][2]);
                v3 = ftanh(acc1[3] + bb2[1][3]);
                h2d[(2 * wv + 1) * 4 + qd][n] = make_uint2(packbf(v0, v1), packbf(v2, v3));
            }
        }
    }
    __syncthreads();

    // layer 3 MFMA: wave wv -> Mtiles wv*4 .. wv*4+3
    {
        bh8 wf3[4][4];
        float bb3[4][4];
#pragma unroll
        for (int mi = 0; mi < 4; ++mi) {
            int mt = wv * 4 + mi;
#pragma unroll
            for (int ks = 0; ks < 4; ++ks) {
                FragU fu;
                uint4 w = w3f[(mt * 4 + ks) * 64 + lane];
                fu.u[0] = w.x; fu.u[1] = w.y; fu.u[2] = w.z; fu.u[3] = w.w;
                wf3[mi][ks] = fu.h;
            }
#pragma unroll
            for (int r = 0; r < 4; ++r)
                bb3[mi][r] = beff3[b * C3 + mt * 16 + qd * 4 + r];
        }
        float vmax[4][4];
#pragma unroll
        for (int mi = 0; mi < 4; ++mi)
#pragma unroll
            for (int r = 0; r < 4; ++r) vmax[mi][r] = -1e30f;

        for (int nb = 0; nb < 8; ++nb) {
            int n = nb * 16 + ln;
            f32x4 acc[4];
#pragma unroll
            for (int mi = 0; mi < 4; ++mi) acc[mi] = (f32x4){0.f, 0.f, 0.f, 0.f};
#pragma unroll
            for (int ks = 0; ks < 4; ++ks) {
                int k4 = ks * 8 + qd * 2;
                uint2 u0 = h2d[k4][n], u1 = h2d[k4 + 1][n];
                FragU fb;
                fb.u[0] = u0.x; fb.u[1] = u0.y; fb.u[2] = u1.x; fb.u[3] = u1.y;
#pragma unroll
                for (int mi = 0; mi < 4; ++mi)
                    acc[mi] = MFMA_BF16(wf3[mi][ks], fb.h, acc[mi], 0, 0, 0);
            }
#pragma unroll
            for (int mi = 0; mi < 4; ++mi)
#pragma unroll
                for (int r = 0; r < 4; ++r)
                    vmax[mi][r] = fmaxf(vmax[mi][r], ftanh(acc[mi][r] + bb3[mi][r]));
        }

#pragma unroll
        for (int mi = 0; mi < 4; ++mi)
#pragma unroll
            for (int r = 0; r < 4; ++r) {
                float v = vmax[mi][r];
                v = fmaxf(v, __shfl_xor(v, 1, 64));
                v = fmaxf(v, __shfl_xor(v, 2, 64));
                v = fmaxf(v, __shfl_xor(v, 4, 64));
                v = fmaxf(v, __shfl_xor(v, 8, 64));
                if (ln == 0)
                    atomicMax(&genc[b * C3 + (wv * 4 + mi) * 16 + qd * 4 + r], encf(v));
            }
    }
}

// FC head + log_softmax
__global__ __launch_bounds__(256) void k_fc(const unsigned* __restrict__ genc,
                                            const float* __restrict__ fc1w,
                                            const float* __restrict__ fc1b,
                                            const float* __restrict__ fc2w,
                                            const float* __restrict__ fc2b,
                                            float* __restrict__ out) {
    __shared__ float gs[C3];
    __shared__ float hs[C2];
    __shared__ float vs[KO];
    __shared__ float red[2];
    int b = blockIdx.x, t = threadIdx.x;
    gs[t] = decf(genc[b * C3 + t]);
    __syncthreads();
    if (t < C2) {
        float a = fc1b[t];
#pragma unroll 8
        for (int i = 0; i < C3; ++i) a = fmaf(gs[i], fc1w[t * C3 + i], a);
        hs[t] = ftanh(a);
    }
    __syncthreads();
    if (t < KO) {
        float a = fc2b[t];
#pragma unroll 8
        for (int i = 0; i < C2; ++i) a = fmaf(hs[i], fc2w[t * C2 + i], a);
        vs[t] = ftanh(a);
    }
    __syncthreads();
    if (t == 0) {
        float m = -1e30f;
        for (int j = 0; j < KO; ++j) m = fmaxf(m, vs[j]);
        float s = 0.0f;
        for (int j = 0; j < KO; ++j) s += __expf(vs[j] - m);
        red[0] = m;
        red[1] = __logf(s);
    }
    __syncthreads();
    if (t < KO) out[b * KO + t] = vs[t] - red[0] - red[1];
}

// ---------- launcher ----------

extern "C" void kernel_launch(void* const* d_in, const int* in_sizes, int n_in,
                              void* d_out, int out_size, void* d_ws, size_t ws_size,
                              hipStream_t stream) {
    const float* x    = (const float*)d_in[0];
    const float* w1   = (const float*)d_in[1];
    const float* b1   = (const float*)d_in[2];
    const float* w2   = (const float*)d_in[3];
    const float* b2   = (const float*)d_in[4];
    const float* w3   = (const float*)d_in[5];
    const float* b3   = (const float*)d_in[6];
    const float* fc1w = (const float*)d_in[7];
    const float* fc1b = (const float*)d_in[8];
    const float* fc2w = (const float*)d_in[9];
    const float* fc2b = (const float*)d_in[10];
    float* out = (float*)d_out;

    // workspace layout (float-indexed, 16B aligned chunks)
    float* W = (float*)d_ws;
    float*    mx1   = W;                      // 128
    float*    beff1 = W + 128;                // 2048
    unsigned* mx2e  = (unsigned*)(W + 2176);  // 2048
    float*    beff2 = W + 4224;               // 4096
    unsigned* mx3e  = (unsigned*)(W + 8320);  // 4096
    float*    beff3 = W + 12416;              // 8192
    unsigned* genc  = (unsigned*)(W + 20608); // 8192
    uint4*    w2f   = (uint4*)(W + 28800);    // 4096 uints
    uint4*    w3f   = (uint4*)(W + 32896);    // 16384 uints

    hipMemsetAsync(mx2e, 0, C1 * B_ * sizeof(unsigned), stream);
    hipMemsetAsync(mx3e, 0, C2 * B_ * sizeof(unsigned), stream);
    hipMemsetAsync(genc, 0, C3 * B_ * sizeof(unsigned), stream);

    k_prep<<<20, 256, 0, stream>>>(w2, w3, w2f, w3f);
    k_rowmax<<<B_ * 3, 256, 0, stream>>>(x, mx1);
    k_beff1<<<B_, 64, 0, stream>>>(mx1, w1, b1, beff1);
    k_passB<<<B_ * 32, 256, 0, stream>>>(x, w1, beff1, mx2e);
    k_beff2<<<B_, 128, 0, stream>>>(mx2e, w2, b2, beff2);
    k_passC_m<<<B_ * 64, 256, 0, stream>>>(x, w1, beff1, w2f, beff2, mx3e);
    k_beff3<<<B_, 256, 0, stream>>>(mx3e, w3, b3, beff3);
    k_passD_m<<<B_ * 64, 256, 0, stream>>>(x, w1, beff1, w2f, beff2, w3f, beff3, genc);
    k_fc<<<B_, 256, 0, stream>>>(genc, fc1w, fc1b, fc2w, fc2b, out);
}

// Round 3
// 217.205 us; speedup vs baseline: 4.7046x; 1.2683x over previous
//
#include <hip/hip_runtime.h>
#include <hip/hip_bf16.h>

#define B_  32
#define N_  8192
#define C1  64
#define C2  128
#define C3  256
#define KO  40

typedef __attribute__((ext_vector_type(8))) short bh8;
typedef __attribute__((ext_vector_type(4))) float f32x4;

union FragU { uint u[4]; bh8 h; uint4 v; };

#define MFMA_BF16 __builtin_amdgcn_mfma_f32_16x16x32_bf16

// ---------- helpers ----------

__device__ __forceinline__ float ftanh(float x) {
    float e = __expf(2.0f * x);
    float r = __builtin_amdgcn_rcpf(e + 1.0f);
    return fmaf(-2.0f, r, 1.0f);
}

__device__ __forceinline__ float waveMax(float v) {
    v = fmaxf(v, __shfl_xor(v, 32, 64));
    v = fmaxf(v, __shfl_xor(v, 16, 64));
    v = fmaxf(v, __shfl_xor(v, 8, 64));
    v = fmaxf(v, __shfl_xor(v, 4, 64));
    v = fmaxf(v, __shfl_xor(v, 2, 64));
    v = fmaxf(v, __shfl_xor(v, 1, 64));
    return v;
}
__device__ __forceinline__ float quadMax(float v) {  // reduce over ln=lane&15
    v = fmaxf(v, __shfl_xor(v, 1, 64));
    v = fmaxf(v, __shfl_xor(v, 2, 64));
    v = fmaxf(v, __shfl_xor(v, 4, 64));
    v = fmaxf(v, __shfl_xor(v, 8, 64));
    return v;
}

// order-preserving float<->uint encoding for atomicMax (0 is identity for reals)
__device__ __forceinline__ unsigned encf(float f) {
    unsigned u = __float_as_uint(f);
    return (u & 0x80000000u) ? ~u : (u | 0x80000000u);
}
__device__ __forceinline__ float decf(unsigned e) {
    return __uint_as_float((e & 0x80000000u) ? (e & 0x7fffffffu) : ~e);
}

__device__ __forceinline__ unsigned f2bf(float f) {
    unsigned u = __float_as_uint(f);
    return (u + 0x7fffu + ((u >> 16) & 1u)) >> 16;
}
__device__ __forceinline__ unsigned packbf(float a, float b) {
    return f2bf(a) | (f2bf(b) << 16);
}

// ---------- setup: rowmax+beff1+zero (blocks 0..31) | weight prep (32..51) ----------

__global__ __launch_bounds__(256) void k_setup(const float* __restrict__ x,
                                               const float* __restrict__ w1,
                                               const float* __restrict__ b1,
                                               const float* __restrict__ w2,
                                               const float* __restrict__ w3,
                                               float* __restrict__ beff1,
                                               unsigned* __restrict__ mx2e,
                                               unsigned* __restrict__ mx3e,
                                               unsigned* __restrict__ genc,
                                               uint4* __restrict__ w2f,
                                               uint4* __restrict__ w3f) {
    int t = threadIdx.x;
    if (blockIdx.x < 32) {
        int b = blockIdx.x;
        // zero the atomic-max buffers for this batch
        if (t < C1) mx2e[b * C1 + t] = 0u;
        if (t < C2) mx3e[b * C2 + t] = 0u;
        genc[b * C3 + t] = 0u;
        // rowmax over 3 coords
        __shared__ float sred[3][4];
        __shared__ float sm[3];
        const float* xb = x + (size_t)b * 3 * N_;
        float m[3] = {-1e30f, -1e30f, -1e30f};
        for (int i = t; i < N_; i += 256) {
            m[0] = fmaxf(m[0], xb[i]);
            m[1] = fmaxf(m[1], xb[N_ + i]);
            m[2] = fmaxf(m[2], xb[2 * N_ + i]);
        }
#pragma unroll
        for (int f = 0; f < 3; ++f) {
            float v = waveMax(m[f]);
            if ((t & 63) == 0) sred[f][t >> 6] = v;
        }
        __syncthreads();
        if (t < 3) sm[t] = fmaxf(fmaxf(sred[t][0], sred[t][1]),
                                 fmaxf(sred[t][2], sred[t][3]));
        __syncthreads();
        if (t < C1) {
            float v = b1[t];
            v -= sm[0] * w1[t * 3 + 0];
            v -= sm[1] * w1[t * 3 + 1];
            v -= sm[2] * w1[t * 3 + 2];
            beff1[b * C1 + t] = v;
        }
    } else {
        // weight prep: fp32 -> bf16 MFMA A-fragments (16x16x32 layout)
        int tid = (blockIdx.x - 32) * 256 + t;  // 0..5119
        const float* src;
        uint4* dst;
        if (tid < 1024) {  // W2: 8 Mt x 2 ks x 64 lanes
            int lane = tid & 63, ks = (tid >> 6) & 1, mt = tid >> 7;
            src = w2 + (mt * 16 + (lane & 15)) * C1 + ks * 32 + (lane >> 4) * 8;
            dst = w2f + tid;
        } else {           // W3: 16 Mt x 4 ks x 64 lanes
            int fj = tid - 1024;
            int lane = fj & 63, ks = (fj >> 6) & 3, mt = fj >> 8;
            src = w3 + (mt * 16 + (lane & 15)) * C2 + ks * 32 + (lane >> 4) * 8;
            dst = w3f + fj;
        }
        uint4 o;
        o.x = packbf(src[0], src[1]);
        o.y = packbf(src[2], src[3]);
        o.z = packbf(src[4], src[5]);
        o.w = packbf(src[6], src[7]);
        *dst = o;
    }
}

// ---------- passB: mx2 = max_n (W1 x + beff1)  (pre-activation; tanh at decode) ----
// 128 blocks (32 b x 4 chunks), 8 points/thread, one reduce at end.

__global__ __launch_bounds__(256) void k_passB(const float* __restrict__ x,
                                               const float* __restrict__ w1,
                                               const float* __restrict__ beff1,
                                               unsigned* __restrict__ mx2e) {
    int b = blockIdx.x >> 2, chunk = blockIdx.x & 3;
    int t = threadIdx.x, lane = t & 63;
    const float* xb = x + (size_t)b * 3 * N_ + chunk * 2048 + t;
    float x0[8], x1[8], x2[8];
#pragma unroll
    for (int i = 0; i < 8; ++i) {
        x0[i] = xb[i * 256];
        x1[i] = xb[N_ + i * 256];
        x2[i] = xb[2 * N_ + i * 256];
    }
    for (int o = 0; o < C1; ++o) {
        float w0 = w1[o * 3 + 0], wa = w1[o * 3 + 1], wb = w1[o * 3 + 2];
        float m = -1e30f;
#pragma unroll
        for (int i = 0; i < 8; ++i)
            m = fmaxf(m, fmaf(x0[i], w0, fmaf(x1[i], wa, x2[i] * wb)));
        m = waveMax(m) + beff1[b * C1 + o];
        if (lane == 0) atomicMax(&mx2e[b * C1 + o], encf(m));
    }
}

__global__ __launch_bounds__(128) void k_beff2(const unsigned* __restrict__ mx2e,
                                               const float* __restrict__ w2,
                                               const float* __restrict__ b2,
                                               float* __restrict__ beff2) {
    __shared__ float m2[C1];
    int b = blockIdx.x, t = threadIdx.x;
    if (t < C1) m2[t] = ftanh(decf(mx2e[b * C1 + t]));
    __syncthreads();
    float a = b2[t];
#pragma unroll
    for (int f = 0; f < C1; ++f) a -= m2[f] * w2[t * C1 + f];
    beff2[b * C2 + t] = a;
}

__global__ __launch_bounds__(256) void k_beff3(const unsigned* __restrict__ mx3e,
                                               const float* __restrict__ w3,
                                               const float* __restrict__ b3,
                                               float* __restrict__ beff3) {
    __shared__ float m3[C2];
    int b = blockIdx.x, t = threadIdx.x;
    if (t < C2) m3[t] = ftanh(decf(mx3e[b * C2 + t]));
    __syncthreads();
    float a = b3[t];
#pragma unroll
    for (int f = 0; f < C2; ++f) a -= m3[f] * w3[t * C2 + f];
    beff3[b * C3 + t] = a;
}

// ---------- MFMA passes ----------
// LDS layout: hv[kk][n] (uint4) = bf16 channels k = kk*8 .. kk*8+7 of point n.
// B-frag for (ks,quad): kk = ks*4 + quad -> ONE ds_read_b128.

// passC: layer1 (VALU) -> layer2 (MFMA) -> pre-act max -> mx3e
__global__ __launch_bounds__(256) void k_passC_m(const float* __restrict__ x,
                                                 const float* __restrict__ w1,
                                                 const float* __restrict__ beff1,
                                                 const uint4* __restrict__ w2f,
                                                 const float* __restrict__ beff2,
                                                 unsigned* __restrict__ mx3e) {
    __shared__ uint4 h1v[8][130];
    int b = blockIdx.x >> 6;
    int nbase = (blockIdx.x & 63) * 128;
    int t = threadIdx.x;
    int p = t & 127, hh = t >> 7;
    int lane = t & 63, wv = t >> 6, qd = lane >> 4, ln = lane & 15;

    {   // layer 1: channels hh*32..+31 for point p
        const float* xb = x + (size_t)b * 3 * N_ + nbase + p;
        float x0 = xb[0], x1 = xb[N_], x2 = xb[2 * N_];
#pragma unroll
        for (int qq = 0; qq < 4; ++qq) {
            int c = hh * 32 + qq * 8;
            float v[8];
#pragma unroll
            for (int s = 0; s < 8; ++s) {
                float a = beff1[b * C1 + c + s];
                a = fmaf(x0, w1[(c + s) * 3 + 0], a);
                a = fmaf(x1, w1[(c + s) * 3 + 1], a);
                a = fmaf(x2, w1[(c + s) * 3 + 2], a);
                v[s] = ftanh(a);
            }
            uint4 pk;
            pk.x = packbf(v[0], v[1]);
            pk.y = packbf(v[2], v[3]);
            pk.z = packbf(v[4], v[5]);
            pk.w = packbf(v[6], v[7]);
            h1v[hh * 4 + qq][p] = pk;
        }
    }
    __syncthreads();

    // layer 2 MFMA: wave wv -> Mtiles {2wv, 2wv+1}
    bh8 wf2[2][2];
#pragma unroll
    for (int mi = 0; mi < 2; ++mi)
#pragma unroll
        for (int ks = 0; ks < 2; ++ks) {
            FragU fu;
            fu.v = w2f[((2 * wv + mi) * 2 + ks) * 64 + lane];
            wf2[mi][ks] = fu.h;
        }

    float vmax[2][4];
#pragma unroll
    for (int mi = 0; mi < 2; ++mi)
#pragma unroll
        for (int r = 0; r < 4; ++r) vmax[mi][r] = -1e30f;

    for (int nb = 0; nb < 8; ++nb) {
        int n = nb * 16 + ln;
        f32x4 acc0 = {0.f, 0.f, 0.f, 0.f};
        f32x4 acc1 = {0.f, 0.f, 0.f, 0.f};
#pragma unroll
        for (int ks = 0; ks < 2; ++ks) {
            FragU fb;
            fb.v = h1v[ks * 4 + qd][n];
            acc0 = MFMA_BF16(wf2[0][ks], fb.h, acc0, 0, 0, 0);
            acc1 = MFMA_BF16(wf2[1][ks], fb.h, acc1, 0, 0, 0);
        }
#pragma unroll
        for (int r = 0; r < 4; ++r) {
            vmax[0][r] = fmaxf(vmax[0][r], acc0[r]);
            vmax[1][r] = fmaxf(vmax[1][r], acc1[r]);
        }
    }

#pragma unroll
    for (int mi = 0; mi < 2; ++mi)
#pragma unroll
        for (int r = 0; r < 4; ++r) {
            int ch = (2 * wv + mi) * 16 + qd * 4 + r;
            float v = quadMax(vmax[mi][r]) + beff2[b * C2 + ch];
            if (ln == 0) atomicMax(&mx3e[b * C2 + ch], encf(v));
        }
}

// passD: layer1 -> layer2 (MFMA, h2 -> LDS) -> layer3 (MFMA) -> pre-act max -> genc
__global__ __launch_bounds__(256) void k_passD_m(const float* __restrict__ x,
                                                 const float* __restrict__ w1,
                                                 const float* __restrict__ beff1,
                                                 const uint4* __restrict__ w2f,
                                                 const float* __restrict__ beff2,
                                                 const uint4* __restrict__ w3f,
                                                 const float* __restrict__ beff3,
                                                 unsigned* __restrict__ genc) {
    __shared__ uint4 h1v[8][130];
    __shared__ uint4 h2v[16][130];
    int b = blockIdx.x >> 6;
    int nbase = (blockIdx.x & 63) * 128;
    int t = threadIdx.x;
    int p = t & 127, hh = t >> 7;
    int lane = t & 63, wv = t >> 6, qd = lane >> 4, ln = lane & 15;

    {   // layer 1
        const float* xb = x + (size_t)b * 3 * N_ + nbase + p;
        float x0 = xb[0], x1 = xb[N_], x2 = xb[2 * N_];
#pragma unroll
        for (int qq = 0; qq < 4; ++qq) {
            int c = hh * 32 + qq * 8;
            float v[8];
#pragma unroll
            for (int s = 0; s < 8; ++s) {
                float a = beff1[b * C1 + c + s];
                a = fmaf(x0, w1[(c + s) * 3 + 0], a);
                a = fmaf(x1, w1[(c + s) * 3 + 1], a);
                a = fmaf(x2, w1[(c + s) * 3 + 2], a);
                v[s] = ftanh(a);
            }
            uint4 pk;
            pk.x = packbf(v[0], v[1]);
            pk.y = packbf(v[2], v[3]);
            pk.z = packbf(v[4], v[5]);
            pk.w = packbf(v[6], v[7]);
            h1v[hh * 4 + qq][p] = pk;
        }
    }
    __syncthreads();

    // layer 2 MFMA -> h2 (tanh) -> LDS
    {
        bh8 wf2[2][2];
        float bb2[2][4];
#pragma unroll
        for (int mi = 0; mi < 2; ++mi) {
            int mt = 2 * wv + mi;
#pragma unroll
            for (int ks = 0; ks < 2; ++ks) {
                FragU fu;
                fu.v = w2f[(mt * 2 + ks) * 64 + lane];
                wf2[mi][ks] = fu.h;
            }
#pragma unroll
            for (int r = 0; r < 4; ++r)
                bb2[mi][r] = beff2[b * C2 + mt * 16 + qd * 4 + r];
        }
        for (int nb = 0; nb < 8; ++nb) {
            int n = nb * 16 + ln;
            f32x4 acc0 = {0.f, 0.f, 0.f, 0.f};
            f32x4 acc1 = {0.f, 0.f, 0.f, 0.f};
#pragma unroll
            for (int ks = 0; ks < 2; ++ks) {
                FragU fb;
                fb.v = h1v[ks * 4 + qd][n];
                acc0 = MFMA_BF16(wf2[0][ks], fb.h, acc0, 0, 0, 0);
                acc1 = MFMA_BF16(wf2[1][ks], fb.h, acc1, 0, 0, 0);
            }
#pragma unroll
            for (int mi = 0; mi < 2; ++mi) {
                f32x4 acc = mi ? acc1 : acc0;
                float v0 = ftanh(acc[0] + bb2[mi][0]);
                float v1 = ftanh(acc[1] + bb2[mi][1]);
                float v2 = ftanh(acc[2] + bb2[mi][2]);
                float v3 = ftanh(acc[3] + bb2[mi][3]);
                int k4 = (2 * wv + mi) * 4 + qd;  // channel block k4*4..+3
                uint2* dst = reinterpret_cast<uint2*>(&h2v[k4 >> 1][n]);
                dst[k4 & 1] = make_uint2(packbf(v0, v1), packbf(v2, v3));
            }
        }
    }
    __syncthreads();

    // layer 3 MFMA: wave wv -> Mtiles wv*4 .. wv*4+3; pre-act max -> genc
    {
        bh8 wf3[4][4];
#pragma unroll
        for (int mi = 0; mi < 4; ++mi)
#pragma unroll
            for (int ks = 0; ks < 4; ++ks) {
                FragU fu;
                fu.v = w3f[((wv * 4 + mi) * 4 + ks) * 64 + lane];
                wf3[mi][ks] = fu.h;
            }
        float vmax[4][4];
#pragma unroll
        for (int mi = 0; mi < 4; ++mi)
#pragma unroll
            for (int r = 0; r < 4; ++r) vmax[mi][r] = -1e30f;

        for (int nb = 0; nb < 8; ++nb) {
            int n = nb * 16 + ln;
            f32x4 acc[4];
#pragma unroll
            for (int mi = 0; mi < 4; ++mi) acc[mi] = (f32x4){0.f, 0.f, 0.f, 0.f};
#pragma unroll
            for (int ks = 0; ks < 4; ++ks) {
                FragU fb;
                fb.v = h2v[ks * 4 + qd][n];
#pragma unroll
                for (int mi = 0; mi < 4; ++mi)
                    acc[mi] = MFMA_BF16(wf3[mi][ks], fb.h, acc[mi], 0, 0, 0);
            }
#pragma unroll
            for (int mi = 0; mi < 4; ++mi)
#pragma unroll
                for (int r = 0; r < 4; ++r)
                    vmax[mi][r] = fmaxf(vmax[mi][r], acc[mi][r]);
        }

#pragma unroll
        for (int mi = 0; mi < 4; ++mi)
#pragma unroll
            for (int r = 0; r < 4; ++r) {
                int ch = (wv * 4 + mi) * 16 + qd * 4 + r;
                float v = quadMax(vmax[mi][r]) + beff3[b * C3 + ch];
                if (ln == 0) atomicMax(&genc[b * C3 + ch], encf(v));
            }
    }
}

// ---------- FC head + log_softmax ----------

__global__ __launch_bounds__(256) void k_fc(const unsigned* __restrict__ genc,
                                            const float* __restrict__ fc1w,
                                            const float* __restrict__ fc1b,
                                            const float* __restrict__ fc2w,
                                            const float* __restrict__ fc2b,
                                            float* __restrict__ out) {
    __shared__ float gs[C3];
    __shared__ float hs[C2];
    __shared__ float vs[KO];
    __shared__ float red[2];
    int b = blockIdx.x, t = threadIdx.x;
    gs[t] = ftanh(decf(genc[b * C3 + t]));
    __syncthreads();
    if (t < C2) {
        float a = fc1b[t];
#pragma unroll 8
        for (int i = 0; i < C3; ++i) a = fmaf(gs[i], fc1w[t * C3 + i], a);
        hs[t] = ftanh(a);
    }
    __syncthreads();
    if (t < KO) {
        float a = fc2b[t];
#pragma unroll 8
        for (int i = 0; i < C2; ++i) a = fmaf(hs[i], fc2w[t * C2 + i], a);
        vs[t] = ftanh(a);
    }
    __syncthreads();
    if (t == 0) {
        float m = -1e30f;
        for (int j = 0; j < KO; ++j) m = fmaxf(m, vs[j]);
        float s = 0.0f;
        for (int j = 0; j < KO; ++j) s += __expf(vs[j] - m);
        red[0] = m;
        red[1] = __logf(s);
    }
    __syncthreads();
    if (t < KO) out[b * KO + t] = vs[t] - red[0] - red[1];
}

// ---------- launcher ----------

extern "C" void kernel_launch(void* const* d_in, const int* in_sizes, int n_in,
                              void* d_out, int out_size, void* d_ws, size_t ws_size,
                              hipStream_t stream) {
    const float* x    = (const float*)d_in[0];
    const float* w1   = (const float*)d_in[1];
    const float* b1   = (const float*)d_in[2];
    const float* w2   = (const float*)d_in[3];
    const float* b2   = (const float*)d_in[4];
    const float* w3   = (const float*)d_in[5];
    const float* b3   = (const float*)d_in[6];
    const float* fc1w = (const float*)d_in[7];
    const float* fc1b = (const float*)d_in[8];
    const float* fc2w = (const float*)d_in[9];
    const float* fc2b = (const float*)d_in[10];
    float* out = (float*)d_out;

    float* W = (float*)d_ws;
    float*    beff1 = W;                      // 2048
    unsigned* mx2e  = (unsigned*)(W + 2048);  // 2048
    float*    beff2 = W + 4096;               // 4096
    unsigned* mx3e  = (unsigned*)(W + 8192);  // 4096
    float*    beff3 = W + 12288;              // 8192
    unsigned* genc  = (unsigned*)(W + 20480); // 8192
    uint4*    w2f   = (uint4*)(W + 28672);    // 4096 uints
    uint4*    w3f   = (uint4*)(W + 32768);    // 16384 uints

    k_setup<<<52, 256, 0, stream>>>(x, w1, b1, w2, w3, beff1, mx2e, mx3e, genc, w2f, w3f);
    k_passB<<<128, 256, 0, stream>>>(x, w1, beff1, mx2e);
    k_beff2<<<B_, 128, 0, stream>>>(mx2e, w2, b2, beff2);
    k_passC_m<<<B_ * 64, 256, 0, stream>>>(x, w1, beff1, w2f, beff2, mx3e);
    k_beff3<<<B_, 256, 0, stream>>>(mx3e, w3, b3, beff3);
    k_passD_m<<<B_ * 64, 256, 0, stream>>>(x, w1, beff1, w2f, beff2, w3f, beff3, genc);
    k_fc<<<B_, 256, 0, stream>>>(genc, fc1w, fc1b, fc2w, fc2b, out);
}

// Round 4
// 177.390 us; speedup vs baseline: 5.7605x; 1.2244x over previous
//
#include <hip/hip_runtime.h>
#include <hip/hip_bf16.h>

#define B_  32
#define N_  8192
#define C1  64
#define C2  128
#define C3  256
#define KO  40

typedef __attribute__((ext_vector_type(8))) short bh8;
typedef __attribute__((ext_vector_type(4))) float f32x4;

union FragU { uint u[4]; bh8 h; uint4 v; };

#define MFMA_BF16 __builtin_amdgcn_mfma_f32_16x16x32_bf16

// ---------- helpers ----------

__device__ __forceinline__ float ftanh(float x) {
    float e = __expf(2.0f * x);
    float r = __builtin_amdgcn_rcpf(e + 1.0f);
    return fmaf(-2.0f, r, 1.0f);
}

__device__ __forceinline__ float waveMax(float v) {
    v = fmaxf(v, __shfl_xor(v, 32, 64));
    v = fmaxf(v, __shfl_xor(v, 16, 64));
    v = fmaxf(v, __shfl_xor(v, 8, 64));
    v = fmaxf(v, __shfl_xor(v, 4, 64));
    v = fmaxf(v, __shfl_xor(v, 2, 64));
    v = fmaxf(v, __shfl_xor(v, 1, 64));
    return v;
}
__device__ __forceinline__ float quadMax(float v) {  // reduce over ln=lane&15
    v = fmaxf(v, __shfl_xor(v, 1, 64));
    v = fmaxf(v, __shfl_xor(v, 2, 64));
    v = fmaxf(v, __shfl_xor(v, 4, 64));
    v = fmaxf(v, __shfl_xor(v, 8, 64));
    return v;
}

// order-preserving float<->uint encoding; 0u is below every real encoding
__device__ __forceinline__ unsigned encf(float f) {
    unsigned u = __float_as_uint(f);
    return (u & 0x80000000u) ? ~u : (u | 0x80000000u);
}
__device__ __forceinline__ float decf(unsigned e) {
    return __uint_as_float((e & 0x80000000u) ? (e & 0x7fffffffu) : ~e);
}

__device__ __forceinline__ unsigned f2bf(float f) {
    unsigned u = __float_as_uint(f);
    return (u + 0x7fffu + ((u >> 16) & 1u)) >> 16;
}
__device__ __forceinline__ unsigned packbf(float a, float b) {
    return f2bf(a) | (f2bf(b) << 16);
}

// ---------- k_scan: blocks 0..255 = x scan (coord max + layer1 preact max);
//                    blocks 256..275 = weight prep ----------

__global__ __launch_bounds__(256) void k_scan(const float* __restrict__ x,
                                              const float* __restrict__ w1,
                                              const float* __restrict__ w2,
                                              const float* __restrict__ w3,
                                              unsigned* __restrict__ mx1e,
                                              unsigned* __restrict__ mx2raw,
                                              uint4* __restrict__ w2f,
                                              uint4* __restrict__ w3f) {
    int t = threadIdx.x;
    if (blockIdx.x < 256) {
        int b = blockIdx.x >> 3, chunk = blockIdx.x & 7;
        int lane = t & 63;
        const float* xb = x + (size_t)b * 3 * N_ + chunk * 1024 + t;
        float x0[4], x1[4], x2[4];
#pragma unroll
        for (int i = 0; i < 4; ++i) {
            x0[i] = xb[i * 256];
            x1[i] = xb[N_ + i * 256];
            x2[i] = xb[2 * N_ + i * 256];
        }
        // per-coordinate max (for beff1)
        float c0 = fmaxf(fmaxf(x0[0], x0[1]), fmaxf(x0[2], x0[3]));
        float c1 = fmaxf(fmaxf(x1[0], x1[1]), fmaxf(x1[2], x1[3]));
        float c2 = fmaxf(fmaxf(x2[0], x2[1]), fmaxf(x2[2], x2[3]));
        c0 = waveMax(c0); c1 = waveMax(c1); c2 = waveMax(c2);
        if (lane == 0) {
            atomicMax(&mx1e[b * 3 + 0], encf(c0));
            atomicMax(&mx1e[b * 3 + 1], encf(c1));
            atomicMax(&mx1e[b * 3 + 2], encf(c2));
        }
        // per-channel max of raw W1.x (beff1 added later in k_beff2)
        for (int o = 0; o < C1; ++o) {
            float w0 = w1[o * 3 + 0], wa = w1[o * 3 + 1], wb = w1[o * 3 + 2];
            float m = -1e30f;
#pragma unroll
            for (int i = 0; i < 4; ++i)
                m = fmaxf(m, fmaf(x0[i], w0, fmaf(x1[i], wa, x2[i] * wb)));
            m = waveMax(m);
            if (lane == 0) atomicMax(&mx2raw[b * C1 + o], encf(m));
        }
    } else {
        // weight prep: fp32 -> bf16 MFMA A-fragments (16x16x32 layout)
        int tid = (blockIdx.x - 256) * 256 + t;  // 0..5119
        const float* src;
        uint4* dst;
        if (tid < 1024) {  // W2: 8 Mt x 2 ks x 64 lanes
            int lane = tid & 63, ks = (tid >> 6) & 1, mt = tid >> 7;
            src = w2 + (mt * 16 + (lane & 15)) * C1 + ks * 32 + (lane >> 4) * 8;
            dst = w2f + tid;
        } else {           // W3: 16 Mt x 4 ks x 64 lanes
            int fj = tid - 1024;
            int lane = fj & 63, ks = (fj >> 6) & 3, mt = fj >> 8;
            src = w3 + (mt * 16 + (lane & 15)) * C2 + ks * 32 + (lane >> 4) * 8;
            dst = w3f + fj;
        }
        uint4 o;
        o.x = packbf(src[0], src[1]);
        o.y = packbf(src[2], src[3]);
        o.z = packbf(src[4], src[5]);
        o.w = packbf(src[6], src[7]);
        *dst = o;
    }
}

// ---------- k_beff2: beff1 from mx1; m2 = tanh(mx2raw + beff1); beff2 ----------

__global__ __launch_bounds__(128) void k_beff2(const unsigned* __restrict__ mx1e,
                                               const unsigned* __restrict__ mx2raw,
                                               const float* __restrict__ w1,
                                               const float* __restrict__ b1,
                                               const float* __restrict__ w2,
                                               const float* __restrict__ b2,
                                               float* __restrict__ beff1,
                                               float* __restrict__ beff2) {
    __shared__ float m2[C1];
    int b = blockIdx.x, t = threadIdx.x;
    if (t < C1) {
        float s0 = decf(mx1e[b * 3 + 0]);
        float s1 = decf(mx1e[b * 3 + 1]);
        float s2 = decf(mx1e[b * 3 + 2]);
        float be = b1[t] - s0 * w1[t * 3 + 0] - s1 * w1[t * 3 + 1] - s2 * w1[t * 3 + 2];
        beff1[b * C1 + t] = be;
        m2[t] = ftanh(decf(mx2raw[b * C1 + t]) + be);
    }
    __syncthreads();
    float a = b2[t];
#pragma unroll
    for (int f = 0; f < C1; ++f) a -= m2[f] * w2[t * C1 + f];
    beff2[b * C2 + t] = a;
}

// ---------- k_passD: layer1 -> layer2 (MFMA, +mx3 tracking, h2->LDS)
//                     -> layer3 (MFMA, raw max -> genc) ----------
// LDS layout: hv[kk][n] (uint4) = bf16 channels kk*8..+7 of point n.
// B-frag for (ks,quad): kk = ks*4 + quad -> ONE ds_read_b128.

__global__ __launch_bounds__(256) void k_passD_m(const float* __restrict__ x,
                                                 const float* __restrict__ w1,
                                                 const float* __restrict__ beff1,
                                                 const uint4* __restrict__ w2f,
                                                 const float* __restrict__ beff2,
                                                 const uint4* __restrict__ w3f,
                                                 unsigned* __restrict__ mx3e,
                                                 unsigned* __restrict__ genc) {
    __shared__ uint4 h1v[8][130];
    __shared__ uint4 h2v[16][130];
    int b = blockIdx.x >> 6;
    int nbase = (blockIdx.x & 63) * 128;
    int t = threadIdx.x;
    int p = t & 127, hh = t >> 7;
    int lane = t & 63, wv = t >> 6, qd = lane >> 4, ln = lane & 15;

    {   // layer 1: channels hh*32..+31 for point p
        const float* xb = x + (size_t)b * 3 * N_ + nbase + p;
        float x0 = xb[0], x1 = xb[N_], x2 = xb[2 * N_];
#pragma unroll
        for (int qq = 0; qq < 4; ++qq) {
            int c = hh * 32 + qq * 8;
            float v[8];
#pragma unroll
            for (int s = 0; s < 8; ++s) {
                float a = beff1[b * C1 + c + s];
                a = fmaf(x0, w1[(c + s) * 3 + 0], a);
                a = fmaf(x1, w1[(c + s) * 3 + 1], a);
                a = fmaf(x2, w1[(c + s) * 3 + 2], a);
                v[s] = ftanh(a);
            }
            uint4 pk;
            pk.x = packbf(v[0], v[1]);
            pk.y = packbf(v[2], v[3]);
            pk.z = packbf(v[4], v[5]);
            pk.w = packbf(v[6], v[7]);
            h1v[hh * 4 + qq][p] = pk;
        }
    }
    __syncthreads();

    // layer 2 MFMA: wave wv -> Mtiles {2wv, 2wv+1}; h2 -> LDS; track mx3
    {
        bh8 wf2[2][2];
        float bb2[2][4];
#pragma unroll
        for (int mi = 0; mi < 2; ++mi) {
            int mt = 2 * wv + mi;
#pragma unroll
            for (int ks = 0; ks < 2; ++ks) {
                FragU fu;
                fu.v = w2f[(mt * 2 + ks) * 64 + lane];
                wf2[mi][ks] = fu.h;
            }
#pragma unroll
            for (int r = 0; r < 4; ++r)
                bb2[mi][r] = beff2[b * C2 + mt * 16 + qd * 4 + r];
        }
        float vmax2[2][4];
#pragma unroll
        for (int mi = 0; mi < 2; ++mi)
#pragma unroll
            for (int r = 0; r < 4; ++r) vmax2[mi][r] = -1e30f;

        for (int nb = 0; nb < 8; ++nb) {
            int n = nb * 16 + ln;
            f32x4 acc0 = {0.f, 0.f, 0.f, 0.f};
            f32x4 acc1 = {0.f, 0.f, 0.f, 0.f};
#pragma unroll
            for (int ks = 0; ks < 2; ++ks) {
                FragU fb;
                fb.v = h1v[ks * 4 + qd][n];
                acc0 = MFMA_BF16(wf2[0][ks], fb.h, acc0, 0, 0, 0);
                acc1 = MFMA_BF16(wf2[1][ks], fb.h, acc1, 0, 0, 0);
            }
#pragma unroll
            for (int mi = 0; mi < 2; ++mi) {
                f32x4 acc = mi ? acc1 : acc0;
                float s0 = acc[0] + bb2[mi][0];
                float s1 = acc[1] + bb2[mi][1];
                float s2 = acc[2] + bb2[mi][2];
                float s3 = acc[3] + bb2[mi][3];
                vmax2[mi][0] = fmaxf(vmax2[mi][0], s0);
                vmax2[mi][1] = fmaxf(vmax2[mi][1], s1);
                vmax2[mi][2] = fmaxf(vmax2[mi][2], s2);
                vmax2[mi][3] = fmaxf(vmax2[mi][3], s3);
                int k4 = (2 * wv + mi) * 4 + qd;  // channel block k4*4..+3
                uint2* dst = reinterpret_cast<uint2*>(&h2v[k4 >> 1][n]);
                dst[k4 & 1] = make_uint2(packbf(ftanh(s0), ftanh(s1)),
                                         packbf(ftanh(s2), ftanh(s3)));
            }
        }
#pragma unroll
        for (int mi = 0; mi < 2; ++mi)
#pragma unroll
            for (int r = 0; r < 4; ++r) {
                float v = quadMax(vmax2[mi][r]);
                if (ln == 0)
                    atomicMax(&mx3e[b * C2 + (2 * wv + mi) * 16 + qd * 4 + r], encf(v));
            }
    }
    __syncthreads();

    // layer 3 MFMA: wave wv -> Mtiles wv*4..+3; raw max -> genc (no bias here)
    {
        bh8 wf3[4][4];
#pragma unroll
        for (int mi = 0; mi < 4; ++mi)
#pragma unroll
            for (int ks = 0; ks < 4; ++ks) {
                FragU fu;
                fu.v = w3f[((wv * 4 + mi) * 4 + ks) * 64 + lane];
                wf3[mi][ks] = fu.h;
            }
        float vmax[4][4];
#pragma unroll
        for (int mi = 0; mi < 4; ++mi)
#pragma unroll
            for (int r = 0; r < 4; ++r) vmax[mi][r] = -1e30f;

        for (int nb = 0; nb < 8; ++nb) {
            int n = nb * 16 + ln;
            f32x4 acc[4];
#pragma unroll
            for (int mi = 0; mi < 4; ++mi) acc[mi] = (f32x4){0.f, 0.f, 0.f, 0.f};
#pragma unroll
            for (int ks = 0; ks < 4; ++ks) {
                FragU fb;
                fb.v = h2v[ks * 4 + qd][n];
#pragma unroll
                for (int mi = 0; mi < 4; ++mi)
                    acc[mi] = MFMA_BF16(wf3[mi][ks], fb.h, acc[mi], 0, 0, 0);
            }
#pragma unroll
            for (int mi = 0; mi < 4; ++mi)
#pragma unroll
                for (int r = 0; r < 4; ++r)
                    vmax[mi][r] = fmaxf(vmax[mi][r], acc[mi][r]);
        }

#pragma unroll
        for (int mi = 0; mi < 4; ++mi)
#pragma unroll
            for (int r = 0; r < 4; ++r) {
                float v = quadMax(vmax[mi][r]);
                if (ln == 0)
                    atomicMax(&genc[b * C3 + (wv * 4 + mi) * 16 + qd * 4 + r], encf(v));
            }
    }
}

// ---------- k_fc: beff3 inline + FC head + log_softmax ----------

__global__ __launch_bounds__(256) void k_fc(const unsigned* __restrict__ mx3e,
                                            const unsigned* __restrict__ genc,
                                            const float* __restrict__ w3,
                                            const float* __restrict__ b3,
                                            const float* __restrict__ fc1w,
                                            const float* __restrict__ fc1b,
                                            const float* __restrict__ fc2w,
                                            const float* __restrict__ fc2b,
                                            float* __restrict__ out) {
    __shared__ float m3[C2];
    __shared__ float gs[C3];
    __shared__ float hs[C2];
    __shared__ float vs[KO];
    __shared__ float red[2];
    int b = blockIdx.x, t = threadIdx.x;
    if (t < C2) m3[t] = ftanh(decf(mx3e[b * C2 + t]));
    __syncthreads();
    {   // beff3 inline, then pooled feature
        float a = b3[t];
#pragma unroll 8
        for (int f = 0; f < C2; ++f) a -= m3[f] * w3[t * C2 + f];
        gs[t] = ftanh(decf(genc[b * C3 + t]) + a);
    }
    __syncthreads();
    if (t < C2) {
        float a = fc1b[t];
#pragma unroll 8
        for (int i = 0; i < C3; ++i) a = fmaf(gs[i], fc1w[t * C3 + i], a);
        hs[t] = ftanh(a);
    }
    __syncthreads();
    if (t < KO) {
        float a = fc2b[t];
#pragma unroll 8
        for (int i = 0; i < C2; ++i) a = fmaf(hs[i], fc2w[t * C2 + i], a);
        vs[t] = ftanh(a);
    }
    __syncthreads();
    if (t == 0) {
        float m = -1e30f;
        for (int j = 0; j < KO; ++j) m = fmaxf(m, vs[j]);
        float s = 0.0f;
        for (int j = 0; j < KO; ++j) s += __expf(vs[j] - m);
        red[0] = m;
        red[1] = __logf(s);
    }
    __syncthreads();
    if (t < KO) out[b * KO + t] = vs[t] - red[0] - red[1];
}

// ---------- launcher ----------

extern "C" void kernel_launch(void* const* d_in, const int* in_sizes, int n_in,
                              void* d_out, int out_size, void* d_ws, size_t ws_size,
                              hipStream_t stream) {
    const float* x    = (const float*)d_in[0];
    const float* w1   = (const float*)d_in[1];
    const float* b1   = (const float*)d_in[2];
    const float* w2   = (const float*)d_in[3];
    const float* b2   = (const float*)d_in[4];
    const float* w3   = (const float*)d_in[5];
    const float* b3   = (const float*)d_in[6];
    const float* fc1w = (const float*)d_in[7];
    const float* fc1b = (const float*)d_in[8];
    const float* fc2w = (const float*)d_in[9];
    const float* fc2b = (const float*)d_in[10];
    float* out = (float*)d_out;

    float* W = (float*)d_ws;
    // zeroed region (contiguous): mx1e | mx2raw | mx3e | genc
    unsigned* mx1e   = (unsigned*)W;           // 128 (96 used)
    unsigned* mx2raw = (unsigned*)(W + 128);   // 2048
    unsigned* mx3e   = (unsigned*)(W + 2176);  // 4096
    unsigned* genc   = (unsigned*)(W + 6272);  // 8192
    float*    beff1  = W + 14464;              // 2048
    float*    beff2  = W + 16512;              // 4096
    uint4*    w2f    = (uint4*)(W + 20608);    // 4096 words
    uint4*    w3f    = (uint4*)(W + 24704);    // 16384 words

    hipMemsetAsync(W, 0, 14464 * sizeof(float), stream);
    k_scan<<<276, 256, 0, stream>>>(x, w1, w2, w3, mx1e, mx2raw, w2f, w3f);
    k_beff2<<<B_, 128, 0, stream>>>(mx1e, mx2raw, w1, b1, w2, b2, beff1, beff2);
    k_passD_m<<<B_ * 64, 256, 0, stream>>>(x, w1, beff1, w2f, beff2, w3f, mx3e, genc);
    k_fc<<<B_, 256, 0, stream>>>(mx3e, genc, w3, b3, fc1w, fc1b, fc2w, fc2b, out);
}